// Round 4
// baseline (2934.713 us; speedup 1.0000x reference)
//
#include <hip/hip_runtime.h>
#include <cmath>

#define PH 512
#define PW 512
#define PLANE (PH * PW)
#define RINGN 128 /* ring slots (pow2); live span 64+2R <= 108 < 128 */
#define RSTR 68   /* floats per ring row; slot*68+lane -> 2 lanes/bank = free */

struct W45 { float w[45]; };

enum { M_FIRST = 0, M_MID = 1, M_LAST = 2, M_MASK = 3 };

__device__ __forceinline__ int clampi(int v, int hi) {
  return v < 0 ? 0 : (v > hi ? hi : v);
}

// ---- H producer: one row (local lr), 8 output cols, conv from global ------
template <int R, bool EDGE>
__device__ __forceinline__ void hprod(const float* __restrict__ src,
                                      float* __restrict__ ring, int lr, int cg,
                                      int x0, int Y0, const W45& wt) {
  constexpr int NW = 8 + 2 * R;
  constexpr int PRE = (4 - (R & 3)) & 3;
  constexpr int NV = (NW + PRE + 3) >> 2;
  const int y = clampi(Y0 + lr - R, PH - 1);
  const float* row = src + (size_t)y * PW;
  const int xs = x0 + cg * 8 - R;
  float win[NV * 4];
  if (!EDGE) {
    const float4* rp = (const float4*)(row + (xs - PRE));
#pragma unroll
    for (int v = 0; v < NV; ++v) *(float4*)&win[v * 4] = rp[v];
  } else {
#pragma unroll
    for (int j = 0; j < NW; ++j) win[PRE + j] = row[clampi(xs + j, PW - 1)];
  }
  float a[8];
#pragma unroll
  for (int i = 0; i < 8; ++i) a[i] = 0.f;
#pragma unroll
  for (int t = 0; t <= 2 * R; ++t) {
    const float wv = wt.w[t];
#pragma unroll
    for (int i = 0; i < 8; ++i) a[i] = fmaf(wv, win[PRE + t + i], a[i]);
  }
  float* dst = ring + (lr & (RINGN - 1)) * RSTR + cg * 8;
  *(float4*)dst = make_float4(a[0], a[1], a[2], a[3]);
  *(float4*)(dst + 4) = make_float4(a[4], a[5], a[6], a[7]);
}

// ---- V conv: 8 consecutive output rows at one column (lane) ---------------
template <int R>
__device__ __forceinline__ void vconv(const float* __restrict__ ring, int lrb,
                                      int lane, const W45& wt, float* a) {
#pragma unroll
  for (int i = 0; i < 8; ++i) a[i] = 0.f;
#pragma unroll
  for (int j = 0; j < 2 * R + 8; ++j) {
    const float v = ring[((lrb + j) & (RINGN - 1)) * RSTR + lane];
#pragma unroll
    for (int i = 0; i < 8; ++i)
      if (i <= j && (j - i) <= 2 * R) a[i] = fmaf(wt.w[j - i], v, a[i]);
  }
}

// ---- fused H+V+blend rolling half-stripe kernel ---------------------------
// block = (plane p, stripe sx 0..7, half h 0..1); 512 threads.
// H rows -> 128-slot LDS ring (slot = lr & 127); 4 chunks x 64 output rows.
template <int R, int MODE>
__global__ __launch_bounds__(512, 4) void fused_kernel(
    const float* __restrict__ s0, const float* __restrict__ s1,
    const float* __restrict__ sm, float* __restrict__ o0,
    float* __restrict__ o1, float* __restrict__ om,
    const float* __restrict__ bmb, float* __restrict__ outp, int cn3, W45 wt) {
  __shared__ float ring0[RINGN * RSTR];
  __shared__ float ring1[RINGN * RSTR];
  const int tid = threadIdx.x;
  const int su = blockIdx.x & 15, sx = su & 7, h = su >> 3;
  const int p = blockIdx.x >> 4;
  const int Y0 = h << 8, x0 = sx << 6;
  const int lane = tid & 63, yg = tid >> 6;
  const int rr = tid >> 3, cg = tid & 7;
  const bool edge = (sx == 0) || (sx == 7);

  const bool ismask = (MODE == M_MASK) || (MODE != M_LAST && p >= cn3);

  if (ismask) {
    const int pm = (MODE == M_MASK) ? p : p - cn3;
    const float* srcm = sm + (size_t)pm * PLANE;
    if (rr < 2 * R) {
      if (edge) hprod<R, true>(srcm, ring0, rr, cg, x0, Y0, wt);
      else      hprod<R, false>(srcm, ring0, rr, cg, x0, Y0, wt);
    }
    __syncthreads();
#pragma unroll 1
    for (int k = 0; k < 4; ++k) {
      const int lr = k * 64 + 2 * R + rr;
      if (edge) hprod<R, true>(srcm, ring0, lr, cg, x0, Y0, wt);
      else      hprod<R, false>(srcm, ring0, lr, cg, x0, Y0, wt);
      __syncthreads();
      float a[8];
      vconv<R>(ring0, k * 64 + yg * 8, lane, wt, a);
      const int ybase = Y0 + k * 64 + yg * 8;
#pragma unroll
      for (int i = 0; i < 8; ++i)
        om[(size_t)pm * PLANE + (size_t)(ybase + i) * PW + x0 + lane] = a[i];
      __syncthreads();
    }
    return;
  }

  // ---- blend path ----
  const float* src0 = s0 + (size_t)p * PLANE;
  const float* src1 = s1 + (size_t)p * PLANE;
  const int n = p / 3;
  const float* mpl = sm + (size_t)n * PLANE;

  if (rr < 2 * R) {
    if (edge) {
      hprod<R, true>(src0, ring0, rr, cg, x0, Y0, wt);
      hprod<R, true>(src1, ring1, rr, cg, x0, Y0, wt);
    } else {
      hprod<R, false>(src0, ring0, rr, cg, x0, Y0, wt);
      hprod<R, false>(src1, ring1, rr, cg, x0, Y0, wt);
    }
  }
  __syncthreads();
#pragma unroll 1
  for (int k = 0; k < 4; ++k) {
    const int lr = k * 64 + 2 * R + rr;
    if (edge) {
      hprod<R, true>(src0, ring0, lr, cg, x0, Y0, wt);
      hprod<R, true>(src1, ring1, lr, cg, x0, Y0, wt);
    } else {
      hprod<R, false>(src0, ring0, lr, cg, x0, Y0, wt);
      hprod<R, false>(src1, ring1, lr, cg, x0, Y0, wt);
    }
    __syncthreads();
    float b0[8], b1[8];
    const int lrb = k * 64 + yg * 8;
    vconv<R>(ring0, lrb, lane, wt, b0);
    vconv<R>(ring1, lrb, lane, wt, b1);
    const int ybase = Y0 + k * 64 + yg * 8;
#pragma unroll
    for (int i = 0; i < 8; ++i) {
      const size_t idx = (size_t)(ybase + i) * PW + x0 + lane;
      const float c0 = src0[idx];
      const float c1 = src1[idx];
      const float m = mpl[idx];
      const size_t oidx = (size_t)p * PLANE + idx;
      if (MODE == M_FIRST) {
        const float l0 = c0 - b0[i], l1 = c1 - b1[i];
        outp[oidx] = l0 + m * (l1 - l0);
        o0[oidx] = b0[i];
        o1[oidx] = b1[i];
      } else if (MODE == M_MID) {
        const float l0 = c0 - b0[i], l1 = c1 - b1[i];
        outp[oidx] += l0 + m * (l1 - l0);
        o0[oidx] = b0[i];
        o1[oidx] = b1[i];
      } else { // M_LAST: fold final (non-blurred) level; b0 cancels in d
        const float d = b1[i] - b0[i];
        const float bmv = bmb[(size_t)n * PLANE + idx];
        outp[oidx] += c0 + m * ((c1 - c0) - d) + bmv * d;
      }
    }
    __syncthreads();
  }
}

// ---- host -----------------------------------------------------------------
static void make_weights(W45& wt, int lvl, int R) {
  double sigma = 1.0;
  for (int i = 0; i < lvl; ++i) sigma *= 2.0;
  double g[45];
  for (int i = 0; i < 45; ++i) {
    double x = i - 22.0;
    g[i] = exp(-(x * x) / (2.0 * sigma * sigma));
  }
  double s = 0.0;
  for (int t = 0; t <= 2 * R; ++t) s += g[t + 22 - R];
  for (int t = 0; t <= 2 * R; ++t) wt.w[t] = (float)(g[t + 22 - R] / s);
}

extern "C" void kernel_launch(void* const* d_in, const int* in_sizes, int n_in,
                              void* d_out, int out_size, void* d_ws,
                              size_t ws_size, hipStream_t stream) {
  const float* img0 = (const float*)d_in[0];
  const float* img1 = (const float*)d_in[1];
  const float* mask = (const float*)d_in[2];
  float* out = (float*)d_out;

  // Truncated radii per level (tail mass <= 5e-6 after renorm)
  constexpr int R0 = 6, R1 = 10, R2 = 18, R3v = 22;
  W45 w0, w1, w2, w3;
  make_weights(w0, 0, R0);
  make_weights(w1, 1, R1);
  make_weights(w2, 2, R2);
  make_weights(w3, 3, R3v);

  const int NTOT = 16;
  // ws planes per image: cur0 x2 sets(6) + cur1 x2 sets(6) + mA + mB + bm = 15
  const size_t perImg = (size_t)15 * PLANE * sizeof(float);
  int CN = 16;
  while (CN > 1 && (size_t)CN * perImg > ws_size) CN >>= 1;

  for (int s = 0; s < NTOT; s += CN) {
    float* base = (float*)d_ws;
    float* c0s0 = base;
    float* c1s0 = c0s0 + (size_t)3 * CN * PLANE;
    float* c0s1 = c1s0 + (size_t)3 * CN * PLANE;
    float* c1s1 = c0s1 + (size_t)3 * CN * PLANE;
    float* mA = c1s1 + (size_t)3 * CN * PLANE;
    float* mB = mA + (size_t)CN * PLANE;
    float* bm = mB + (size_t)CN * PLANE;

    const float* in0 = img0 + (size_t)s * 3 * PLANE;
    const float* in1 = img1 + (size_t)s * 3 * PLANE;
    const float* inm = mask + (size_t)s * PLANE;
    float* o = out + (size_t)s * 3 * PLANE;

    const int cn3 = 3 * CN;
    const dim3 blk(512);
    const int gAll = (cn3 + CN) * 16; // blend + mask blocks
    const int gBld = cn3 * 16;
    const int gMsk = CN * 16;

    // L0: inputs from d_in; writes cur set0 + mA + out
    hipLaunchKernelGGL((fused_kernel<R0, M_FIRST>), dim3(gAll), blk, 0, stream,
                       in0, in1, inm, c0s0, c1s0, mA, (const float*)nullptr, o,
                       cn3, w0);
    // L1: set0 + mA -> set1 + mB
    hipLaunchKernelGGL((fused_kernel<R1, M_MID>), dim3(gAll), blk, 0, stream,
                       c0s0, c1s0, mA, c0s1, c1s1, mB, (const float*)nullptr, o,
                       cn3, w1);
    // L2: set1 + mB -> set0 + mA
    hipLaunchKernelGGL((fused_kernel<R2, M_MID>), dim3(gAll), blk, 0, stream,
                       c0s1, c1s1, mB, c0s0, c1s0, mA, (const float*)nullptr, o,
                       cn3, w2);
    // L3a: mask blur mA -> bm
    hipLaunchKernelGGL((fused_kernel<R3v, M_MASK>), dim3(gMsk), blk, 0, stream,
                       (const float*)nullptr, (const float*)nullptr, mA,
                       (float*)nullptr, (float*)nullptr, bm,
                       (const float*)nullptr, o, cn3, w3);
    // L3b: blend + folded final level
    hipLaunchKernelGGL((fused_kernel<R3v, M_LAST>), dim3(gBld), blk, 0, stream,
                       c0s0, c1s0, mA, (float*)nullptr, (float*)nullptr,
                       (float*)nullptr, bm, o, cn3, w3);
  }
}

// Round 5
// 1074.826 us; speedup vs baseline: 2.7304x; 2.7304x over previous
//
#include <hip/hip_runtime.h>
#include <cmath>

#define PH 512
#define PW 512
#define PLANE (PH * PW)
#define RINGN 128 /* ring slots (pow2); live span 64+2R <= 108 < 128 */
#define RSTR 68   /* floats per ring row; slot*68+lane -> 2 lanes/bank = free */

struct W45 { float w[45]; };

enum { F0 = 0, FMID = 1, MONLY = 2, DLAST = 3 };

__device__ __forceinline__ int clampi(int v, int hi) {
  return v < 0 ? 0 : (v > hi ? hi : v);
}

// ---- H producer: one row (local lr), 8 output cols, conv from global ------
// DUAL: window = sA - sB (round 0 computes D0 = img1 - img0 on the fly; R=6
// only there, so the doubled load window stays small).
template <int R, bool EDGE, bool DUAL>
__device__ __forceinline__ void hprod(const float* __restrict__ sA,
                                      const float* __restrict__ sB,
                                      float* __restrict__ ring, int lr, int cg,
                                      int x0, int Y0, const W45& wt) {
  constexpr int NW = 8 + 2 * R;
  constexpr int PRE = (4 - (R & 3)) & 3;
  constexpr int NV = (NW + PRE + 3) >> 2;
  const int y = clampi(Y0 + lr - R, PH - 1);
  const size_t roff = (size_t)y * PW;
  const int xs = x0 + cg * 8 - R;
  float win[NV * 4];
  if (!EDGE) {
    const float4* ra = (const float4*)(sA + roff + (xs - PRE));
#pragma unroll
    for (int v = 0; v < NV; ++v) *(float4*)&win[v * 4] = ra[v];
    if (DUAL) {
      const float4* rb = (const float4*)(sB + roff + (xs - PRE));
#pragma unroll
      for (int v = 0; v < NV; ++v) {
        float4 t = rb[v];
        win[v * 4 + 0] = t.x - win[v * 4 + 0];
        win[v * 4 + 1] = t.y - win[v * 4 + 1];
        win[v * 4 + 2] = t.z - win[v * 4 + 2];
        win[v * 4 + 3] = t.w - win[v * 4 + 3];
      }
    }
  } else {
#pragma unroll
    for (int j = 0; j < NW; ++j) {
      const int gx = clampi(xs + j, PW - 1);
      win[PRE + j] = DUAL ? (sB[roff + gx] - sA[roff + gx]) : sA[roff + gx];
    }
  }
  float a[8];
#pragma unroll
  for (int i = 0; i < 8; ++i) a[i] = 0.f;
#pragma unroll
  for (int t = 0; t <= 2 * R; ++t) {
    const float wv = wt.w[t];
#pragma unroll
    for (int i = 0; i < 8; ++i) a[i] = fmaf(wv, win[PRE + t + i], a[i]);
  }
  float* dst = ring + (lr & (RINGN - 1)) * RSTR + cg * 8;
  *(float4*)dst = make_float4(a[0], a[1], a[2], a[3]);
  *(float4*)(dst + 4) = make_float4(a[4], a[5], a[6], a[7]);
}
// NOTE on DUAL sign: we want D = img1 - img0; caller passes sA=img0, sB=img1,
// non-EDGE path computes t(sB) - win(sA) = img1 - img0; EDGE path sB - sA. OK.

// ---- V conv: 8 consecutive output rows at one column (lane) ---------------
template <int R>
__device__ __forceinline__ void vconv(const float* __restrict__ ring, int lrb,
                                      int lane, const W45& wt, float* a) {
#pragma unroll
  for (int i = 0; i < 8; ++i) a[i] = 0.f;
#pragma unroll
  for (int j = 0; j < 2 * R + 8; ++j) {
    const float v = ring[((lrb + j) & (RINGN - 1)) * RSTR + lane];
#pragma unroll
    for (int i = 0; i < 8; ++i)
      if (i <= j && (j - i) <= 2 * R) a[i] = fmaf(wt.w[j - i], v, a[i]);
  }
}

// ---- fused H+V+accumulate rolling half-stripe kernel ----------------------
// Telescoped form: out = img0 + sum_l Gm_l*(D_l - D_{l+1}) + Gm_4*D_4.
// Each block owns one plane's 64-wide x 256-tall half-stripe; one LDS ring.
template <int R, int MODE>
__global__ __launch_bounds__(512) void fused_kernel(
    const float* __restrict__ pD, const float* __restrict__ pI0,
    const float* __restrict__ pI1, const float* __restrict__ pM,
    const float* __restrict__ pM4, float* __restrict__ oD,
    float* __restrict__ oM, float* __restrict__ pOut, int cn3, W45 wt) {
  __shared__ float ring[RINGN * RSTR];
  const int tid = threadIdx.x;
  const int su = blockIdx.x & 15, sx = su & 7, h = su >> 3;
  const int p = blockIdx.x >> 4;
  const int Y0 = h << 8, x0 = sx << 6;
  const int lane = tid & 63, yg = tid >> 6;
  const int rr = tid >> 3, cg = tid & 7;
  const bool edge = (sx == 0) || (sx == 7);

  const bool ismask = (MODE == MONLY) || (MODE != DLAST && p >= cn3);

  if (ismask) {
    const int pm = (MODE == MONLY) ? p : p - cn3;
    const float* src = pM + (size_t)pm * PLANE;
    float* dst = oM + (size_t)pm * PLANE;
    if (rr < 2 * R) {
      if (edge) hprod<R, true, false>(src, nullptr, ring, rr, cg, x0, Y0, wt);
      else      hprod<R, false, false>(src, nullptr, ring, rr, cg, x0, Y0, wt);
    }
    __syncthreads();
#pragma unroll 1
    for (int k = 0; k < 4; ++k) {
      const int lr = k * 64 + 2 * R + rr;
      if (edge) hprod<R, true, false>(src, nullptr, ring, lr, cg, x0, Y0, wt);
      else      hprod<R, false, false>(src, nullptr, ring, lr, cg, x0, Y0, wt);
      __syncthreads();
      float a[8];
      vconv<R>(ring, k * 64 + yg * 8, lane, wt, a);
      const int ybase = Y0 + k * 64 + yg * 8;
#pragma unroll
      for (int i = 0; i < 8; ++i)
        dst[(size_t)(ybase + i) * PW + x0 + lane] = a[i];
      __syncthreads();
    }
    return;
  }

  // ---- D path ----
  const int n = p / 3;
  const size_t pof = (size_t)p * PLANE;
  const size_t mof = (size_t)n * PLANE;
  const float* srcD = (MODE == F0) ? nullptr : pD + pof;
  const float* i0 = (MODE == F0) ? pI0 + pof : nullptr;
  const float* i1 = (MODE == F0) ? pI1 + pof : nullptr;

  if (rr < 2 * R) {
    if (MODE == F0) {
      if (edge) hprod<R, true, true>(i0, i1, ring, rr, cg, x0, Y0, wt);
      else      hprod<R, false, true>(i0, i1, ring, rr, cg, x0, Y0, wt);
    } else {
      if (edge) hprod<R, true, false>(srcD, nullptr, ring, rr, cg, x0, Y0, wt);
      else      hprod<R, false, false>(srcD, nullptr, ring, rr, cg, x0, Y0, wt);
    }
  }
  __syncthreads();
#pragma unroll 1
  for (int k = 0; k < 4; ++k) {
    const int lr = k * 64 + 2 * R + rr;
    if (MODE == F0) {
      if (edge) hprod<R, true, true>(i0, i1, ring, lr, cg, x0, Y0, wt);
      else      hprod<R, false, true>(i0, i1, ring, lr, cg, x0, Y0, wt);
    } else {
      if (edge) hprod<R, true, false>(srcD, nullptr, ring, lr, cg, x0, Y0, wt);
      else      hprod<R, false, false>(srcD, nullptr, ring, lr, cg, x0, Y0, wt);
    }
    __syncthreads();
    float b[8];
    vconv<R>(ring, k * 64 + yg * 8, lane, wt, b);
    const int ybase = Y0 + k * 64 + yg * 8;
#pragma unroll
    for (int i = 0; i < 8; ++i) {
      const size_t idx = (size_t)(ybase + i) * PW + x0 + lane;
      if (MODE == F0) {
        const float v0 = i0[idx], v1 = i1[idx];
        const float m = pM[mof + idx];
        pOut[pof + idx] = v0 + m * ((v1 - v0) - b[i]);
        oD[pof + idx] = b[i];
      } else if (MODE == FMID) {
        const float Ds = srcD[idx];
        const float m = pM[mof + idx];
        pOut[pof + idx] += m * (Ds - b[i]);
        oD[pof + idx] = b[i];
      } else { // DLAST: += Gm3*(D3 - D4) + Gm4*D4 ; D4 never stored
        const float Ds = srcD[idx];
        const float m3 = pM[mof + idx];
        const float m4 = pM4[mof + idx];
        pOut[pof + idx] += m3 * (Ds - b[i]) + m4 * b[i];
      }
    }
    __syncthreads();
  }
}

// ---- host -----------------------------------------------------------------
static void make_weights(W45& wt, int lvl, int R) {
  double sigma = 1.0;
  for (int i = 0; i < lvl; ++i) sigma *= 2.0;
  double g[45];
  for (int i = 0; i < 45; ++i) {
    double x = i - 22.0;
    g[i] = exp(-(x * x) / (2.0 * sigma * sigma));
  }
  double s = 0.0;
  for (int t = 0; t <= 2 * R; ++t) s += g[t + 22 - R];
  for (int t = 0; t <= 2 * R; ++t) wt.w[t] = (float)(g[t + 22 - R] / s);
}

extern "C" void kernel_launch(void* const* d_in, const int* in_sizes, int n_in,
                              void* d_out, int out_size, void* d_ws,
                              size_t ws_size, hipStream_t stream) {
  const float* img0 = (const float*)d_in[0];
  const float* img1 = (const float*)d_in[1];
  const float* mask = (const float*)d_in[2];
  float* out = (float*)d_out;

  constexpr int R0 = 6, R1 = 10, R2 = 18, R3v = 22;
  W45 w0, w1, w2, w3;
  make_weights(w0, 0, R0);
  make_weights(w1, 1, R1);
  make_weights(w2, 2, R2);
  make_weights(w3, 3, R3v);

  const int NTOT = 16;
  // ws planes per image: D_A(3) + D_B(3) + m_A(1) + m_B(1) = 8
  const size_t perImg = (size_t)8 * PLANE * sizeof(float);
  int CN = 16;
  while (CN > 1 && (size_t)CN * perImg > ws_size) CN >>= 1;

  for (int s = 0; s < NTOT; s += CN) {
    float* base = (float*)d_ws;
    float* DA = base;
    float* DB = DA + (size_t)3 * CN * PLANE;
    float* mA = DB + (size_t)3 * CN * PLANE;
    float* mB = mA + (size_t)CN * PLANE;

    const float* in0 = img0 + (size_t)s * 3 * PLANE;
    const float* in1 = img1 + (size_t)s * 3 * PLANE;
    const float* inm = mask + (size_t)s * PLANE;
    float* o = out + (size_t)s * 3 * PLANE;

    const int cn3 = 3 * CN;
    const dim3 blk(512);
    const int gAll = (cn3 + CN) * 16;
    const int gD = cn3 * 16;
    const int gM = CN * 16;

    // r0: D blocks read img0/img1/mask; mask blocks mask->mA. out initialized.
    hipLaunchKernelGGL((fused_kernel<R0, F0>), dim3(gAll), blk, 0, stream,
                       (const float*)nullptr, in0, in1, inm,
                       (const float*)nullptr, DA, mA, o, cn3, w0);
    // r1: DA,mA -> DB,mB ; out += mA*(D1 - D2)
    hipLaunchKernelGGL((fused_kernel<R1, FMID>), dim3(gAll), blk, 0, stream,
                       DA, (const float*)nullptr, (const float*)nullptr, mA,
                       (const float*)nullptr, DB, mB, o, cn3, w1);
    // r2: DB,mB -> DA,mA ; out += mB*(D2 - D3)
    hipLaunchKernelGGL((fused_kernel<R2, FMID>), dim3(gAll), blk, 0, stream,
                       DB, (const float*)nullptr, (const float*)nullptr, mB,
                       (const float*)nullptr, DA, mA, o, cn3, w2);
    // r3m: mA (Gm3) -> mB (Gm4)
    hipLaunchKernelGGL((fused_kernel<R3v, MONLY>), dim3(gM), blk, 0, stream,
                       (const float*)nullptr, (const float*)nullptr,
                       (const float*)nullptr, mA, (const float*)nullptr,
                       (float*)nullptr, mB, o, cn3, w3);
    // r3d: out += mA*(D3 - D4) + mB*D4
    hipLaunchKernelGGL((fused_kernel<R3v, DLAST>), dim3(gD), blk, 0, stream,
                       DA, (const float*)nullptr, (const float*)nullptr, mA, mB,
                       (float*)nullptr, (float*)nullptr, o, cn3, w3);
  }
}

// Round 6
// 330.523 us; speedup vs baseline: 8.8790x; 3.2519x over previous
//
#include <hip/hip_runtime.h>
#include <cmath>

#define PH 512
#define PW 512
#define PLANE (PH * PW)
#define RS 68 /* V-window row stride (floats): conflict-free column reads */
#define PHYS(i) (((i) & 7) * 70 + ((i) >> 3)) /* hpass staged-row swizzle */

struct W45 { float w[45]; };

enum { V_F0 = 0, V_MID = 1, V_L3D = 2, V_MONLY = 3 };

__device__ __forceinline__ int clampi(int v, int hi) {
  return v < 0 ? 0 : (v > hi ? hi : v);
}
__device__ __forceinline__ void ldf8(const float* __restrict__ p, float* v) {
  float4 a = *(const float4*)p, b = *(const float4*)(p + 4);
  v[0] = a.x; v[1] = a.y; v[2] = a.z; v[3] = a.w;
  v[4] = b.x; v[5] = b.y; v[6] = b.z; v[7] = b.w;
}
__device__ __forceinline__ void stf8(float* __restrict__ p, const float* v) {
  *(float4*)p = make_float4(v[0], v[1], v[2], v[3]);
  *(float4*)(p + 4) = make_float4(v[4], v[5], v[6], v[7]);
}

// ---------------- horizontal pass (R1 structure, templated radius) ---------
// block = 256 = 4 rows x 64 lanes; each lane computes 8 consecutive x.
// grid.x = nplanes * 128. LV0: D planes stage (in1-in0), m planes stage mask.
template <int R, bool LV0>
__global__ __launch_bounds__(256) void hpass_tele(
    const float* __restrict__ S, const float* __restrict__ in0,
    const float* __restrict__ in1, const float* __restrict__ inm,
    float* __restrict__ tmp, int cn3, W45 wt) {
  const int tid = threadIdx.x;
  const int ry = tid >> 6, lr = tid & 63;
  const int p = blockIdx.x >> 7;
  const int y = ((blockIdx.x & 127) << 2) + ry;

  __shared__ float lds[4][8 * 70];
  if (LV0) {
    if (p < cn3) {
      const float* rA = in0 + (size_t)p * PLANE + (size_t)y * PW;
      const float* rB = in1 + (size_t)p * PLANE + (size_t)y * PW;
      for (int i = lr; i < PW + 2 * R; i += 64) {
        const int gx = clampi(i - R, PW - 1);
        lds[ry][PHYS(i)] = rB[gx] - rA[gx]; // D0 = img1 - img0
      }
    } else {
      const float* rM = inm + (size_t)(p - cn3) * PLANE + (size_t)y * PW;
      for (int i = lr; i < PW + 2 * R; i += 64) {
        lds[ry][PHYS(i)] = rM[clampi(i - R, PW - 1)];
      }
    }
  } else {
    const float* row = S + (size_t)p * PLANE + (size_t)y * PW;
    for (int i = lr; i < PW + 2 * R; i += 64) {
      lds[ry][PHYS(i)] = row[clampi(i - R, PW - 1)];
    }
  }
  __syncthreads();

  const int x0 = lr << 3;
  float win[8 + 2 * R];
#pragma unroll
  for (int j = 0; j < 8 + 2 * R; ++j) win[j] = lds[ry][PHYS(x0 + j)];
  float a[8];
#pragma unroll
  for (int i = 0; i < 8; ++i) a[i] = 0.f;
#pragma unroll
  for (int t = 0; t <= 2 * R; ++t) {
    const float wv = wt.w[t];
#pragma unroll
    for (int i = 0; i < 8; ++i) a[i] = fmaf(wv, win[t + i], a[i]);
  }
  float4* drow = (float4*)(tmp + (size_t)p * PLANE + (size_t)y * PW + x0);
  drow[0] = make_float4(a[0], a[1], a[2], a[3]);
  drow[1] = make_float4(a[4], a[5], a[6], a[7]);
}

// ---------------- vertical pass + telescoped epilogue ----------------------
// block = 512 thr, 64x64 output tile, one plane. Single LDS window buffer;
// transpose-stash (stride 65 -> conflict-free both ways) for float4 epilogue.
template <int R, int MODE>
__global__ __launch_bounds__(512) void vpass_tele(
    const float* __restrict__ tmp, const float* __restrict__ S,
    const float* __restrict__ Sm, const float* __restrict__ Gm4,
    const float* __restrict__ in0, const float* __restrict__ in1,
    const float* __restrict__ inm, float* __restrict__ oS,
    float* __restrict__ oM, float* __restrict__ outp, int cn3, W45 wt) {
  constexpr int VWIN = 64 + 2 * R;
  __shared__ float buf[VWIN * RS];
  const int tid = threadIdx.x;
  const int lane = tid & 63, yg = tid >> 6;
  const int p = blockIdx.x >> 6, t = blockIdx.x & 63;
  const int x0 = (t & 7) << 6, y0 = (t >> 3) << 6;
  const int ey = tid >> 3, exq = (tid & 7) << 3;
  const size_t erow = (size_t)(y0 + ey) * PW + x0 + exq;

  const bool ismask = (MODE == V_MONLY) || (MODE != V_L3D && p >= cn3);
  const int pm = ismask ? ((MODE == V_MONLY) ? p : p - cn3) : 0;

  // ---- load vertical window (float4, coalesced) ----
  {
    const float* src =
        tmp + (size_t)(ismask ? (cn3 + pm) : p) * PLANE;
    for (int idx = tid; idx < VWIN * 16; idx += 512) {
      const int row = idx >> 4, c4 = (idx & 15) << 2;
      const int gy = clampi(y0 + row - R, PH - 1);
      *(float4*)&buf[row * RS + c4] =
          *(const float4*)&src[(size_t)gy * PW + x0 + c4];
    }
  }
  __syncthreads();

  // ---- V conv: 8 consecutive rows at column `lane` ----
  float win[8 + 2 * R];
#pragma unroll
  for (int j = 0; j < 8 + 2 * R; ++j)
    win[j] = buf[((yg << 3) + j) * RS + lane];
  float b[8];
#pragma unroll
  for (int i = 0; i < 8; ++i) b[i] = 0.f;
#pragma unroll
  for (int t_ = 0; t_ <= 2 * R; ++t_) {
    const float wv = wt.w[t_];
#pragma unroll
    for (int i = 0; i < 8; ++i) b[i] = fmaf(wv, win[t_ + i], b[i]);
  }

  // ---- transpose stash -> each thread owns 8 consecutive x at one y ----
  __syncthreads();
#pragma unroll
  for (int i = 0; i < 8; ++i) buf[lane * 65 + (yg << 3) + i] = b[i];
  __syncthreads();
  float bs[8];
#pragma unroll
  for (int j = 0; j < 8; ++j) bs[j] = buf[(exq + j) * 65 + ey];

  if (MODE == V_MONLY || ismask) {
    stf8(oM + (size_t)pm * PLANE + erow, bs);
    return;
  }

  const int n = p / 3;
  float o[8];
  if (MODE == V_F0) {
    float v0[8], v1[8], m[8];
    ldf8(in0 + (size_t)p * PLANE + erow, v0);
    ldf8(in1 + (size_t)p * PLANE + erow, v1);
    ldf8(inm + (size_t)n * PLANE + erow, m);
#pragma unroll
    for (int j = 0; j < 8; ++j)
      o[j] = v0[j] + m[j] * ((v1[j] - v0[j]) - bs[j]);
    stf8(outp + (size_t)p * PLANE + erow, o);
    stf8(oS + (size_t)p * PLANE + erow, bs);
  } else if (MODE == V_MID) {
    float D[8], m[8], pv[8];
    ldf8(S + (size_t)p * PLANE + erow, D);
    ldf8(Sm + (size_t)n * PLANE + erow, m);
    float* op = outp + (size_t)p * PLANE + erow;
    ldf8(op, pv);
#pragma unroll
    for (int j = 0; j < 8; ++j) o[j] = pv[j] + m[j] * (D[j] - bs[j]);
    stf8(op, o);
    stf8(oS + (size_t)p * PLANE + erow, bs);
  } else { // V_L3D: out += Gm3*(D3 - D4) + Gm4*D4
    float D[8], m3[8], m4[8], pv[8];
    ldf8(S + (size_t)p * PLANE + erow, D);
    ldf8(Sm + (size_t)n * PLANE + erow, m3);
    ldf8(Gm4 + (size_t)n * PLANE + erow, m4);
    float* op = outp + (size_t)p * PLANE + erow;
    ldf8(op, pv);
#pragma unroll
    for (int j = 0; j < 8; ++j)
      o[j] = pv[j] + m3[j] * (D[j] - bs[j]) + m4[j] * bs[j];
    stf8(op, o);
  }
}

// ---------------- host -----------------------------------------------------
static void make_weights(W45& wt, int lvl, int R) {
  double sigma = 1.0;
  for (int i = 0; i < lvl; ++i) sigma *= 2.0;
  double g[45];
  for (int i = 0; i < 45; ++i) {
    double x = i - 22.0;
    g[i] = exp(-(x * x) / (2.0 * sigma * sigma));
  }
  double s = 0.0;
  for (int t = 0; t <= 2 * R; ++t) s += g[t + 22 - R];
  for (int t = 0; t <= 2 * R; ++t) wt.w[t] = (float)(g[t + 22 - R] / s);
}

extern "C" void kernel_launch(void* const* d_in, const int* in_sizes, int n_in,
                              void* d_out, int out_size, void* d_ws,
                              size_t ws_size, hipStream_t stream) {
  const float* img0 = (const float*)d_in[0];
  const float* img1 = (const float*)d_in[1];
  const float* mask = (const float*)d_in[2];
  float* out = (float*)d_out;

  constexpr int R0 = 6, R1 = 10, R2 = 18, R3v = 22;
  W45 w0, w1, w2, w3;
  make_weights(w0, 0, R0);
  make_weights(w1, 1, R1);
  make_weights(w2, 2, R2);
  make_weights(w3, 3, R3v);

  const int NTOT = 16;
  // ws planes/img: S_A(4) + S_B(4) + tmp(4) = 12
  const size_t perImg = (size_t)12 * PLANE * sizeof(float);
  int CN = 16;
  while (CN > 1 && (size_t)CN * perImg > ws_size) CN >>= 1;

  for (int s = 0; s < NTOT; s += CN) {
    float* SA = (float*)d_ws;                      // [D:3CN][m:CN]
    float* SB = SA + (size_t)4 * CN * PLANE;
    float* tmp = SB + (size_t)4 * CN * PLANE;

    const float* in0 = img0 + (size_t)s * 3 * PLANE;
    const float* in1 = img1 + (size_t)s * 3 * PLANE;
    const float* inm = mask + (size_t)s * PLANE;
    float* o = out + (size_t)s * 3 * PLANE;

    const int cn3 = 3 * CN;
    float* SAm = SA + (size_t)cn3 * PLANE;
    float* SBm = SB + (size_t)cn3 * PLANE;
    const float* np_ = nullptr;
    const dim3 hb(256), vb(512);
    const int hg = 4 * CN * 128;
    const int vg = 4 * CN * 64;
    const int vgM = CN * 64;
    const int vgD = 3 * CN * 64;

    // L0: stage D0=in1-in0 & mask -> tmp; V: out=i0+m*(D0-D1), SA.D=D1, SA.m=Gm1
    hipLaunchKernelGGL((hpass_tele<R0, true>), dim3(hg), hb, 0, stream, np_,
                       in0, in1, inm, tmp, cn3, w0);
    hipLaunchKernelGGL((vpass_tele<R0, V_F0>), dim3(vg), vb, 0, stream, tmp,
                       np_, np_, np_, in0, in1, inm, SA, SAm, o, cn3, w0);
    // L1: SA -> tmp; out += Gm1*(D1-D2); SB.D=D2, SB.m=Gm2
    hipLaunchKernelGGL((hpass_tele<R1, false>), dim3(hg), hb, 0, stream, SA,
                       np_, np_, np_, tmp, cn3, w1);
    hipLaunchKernelGGL((vpass_tele<R1, V_MID>), dim3(vg), vb, 0, stream, tmp,
                       SA, SAm, np_, np_, np_, np_, SB, SBm, o, cn3, w1);
    // L2: SB -> tmp; out += Gm2*(D2-D3); SA.D=D3, SA.m=Gm3
    hipLaunchKernelGGL((hpass_tele<R2, false>), dim3(hg), hb, 0, stream, SB,
                       np_, np_, np_, tmp, cn3, w2);
    hipLaunchKernelGGL((vpass_tele<R2, V_MID>), dim3(vg), vb, 0, stream, tmp,
                       SB, SBm, np_, np_, np_, np_, SA, SAm, o, cn3, w2);
    // L3: SA -> tmp; Gm4 = V(tmp.m) -> SBm; out += Gm3*(D3-D4)+Gm4*D4
    hipLaunchKernelGGL((hpass_tele<R3v, false>), dim3(hg), hb, 0, stream, SA,
                       np_, np_, np_, tmp, cn3, w3);
    hipLaunchKernelGGL((vpass_tele<R3v, V_MONLY>), dim3(vgM), vb, 0, stream,
                       tmp, np_, np_, np_, np_, np_, np_, (float*)nullptr, SBm,
                       o, cn3, w3);
    hipLaunchKernelGGL((vpass_tele<R3v, V_L3D>), dim3(vgD), vb, 0, stream, tmp,
                       SA, SAm, SBm, np_, np_, np_, (float*)nullptr,
                       (float*)nullptr, o, cn3, w3);
  }
}

// Round 7
// 265.480 us; speedup vs baseline: 11.0544x; 1.2450x over previous
//
#include <hip/hip_runtime.h>
#include <cmath>

#define PH 512
#define PW 512
#define PLANE (PH * PW)
#define RS 68 /* V-window row stride (floats): conflict-free column reads */
#define PHYS(i) (((i) & 7) * 70 + ((i) >> 3)) /* hpass staged-row swizzle */

struct W45 { float w[45]; };

enum { V_F0 = 0, V_MID = 1, V_L3D = 2, V_MONLY = 3 };

__device__ __forceinline__ int clampi(int v, int hi) {
  return v < 0 ? 0 : (v > hi ? hi : v);
}
// XCD-aware bijective chunked swizzle (all grids here are multiples of 8)
__device__ __forceinline__ int swz(int bid, int nwg) {
  const int q = nwg >> 3;
  return (bid & 7) * q + (bid >> 3);
}
__device__ __forceinline__ float bf2f(ushort s) {
  return __uint_as_float((unsigned)s << 16);
}
__device__ __forceinline__ ushort f2bf(float f) { // RNE
  unsigned x = __float_as_uint(f);
  return (ushort)((x + 0x7FFF + ((x >> 16) & 1)) >> 16);
}
union BU { uint4 q; ushort u[8]; };
__device__ __forceinline__ void ldb8(const ushort* __restrict__ p, float* v) {
  BU b;
  b.q = *(const uint4*)p;
#pragma unroll
  for (int j = 0; j < 8; ++j) v[j] = bf2f(b.u[j]);
}
__device__ __forceinline__ void stb8(ushort* __restrict__ p, const float* v) {
  BU b;
#pragma unroll
  for (int j = 0; j < 8; ++j) b.u[j] = f2bf(v[j]);
  *(uint4*)p = b.q;
}
__device__ __forceinline__ void ldf8(const float* __restrict__ p, float* v) {
  float4 a = *(const float4*)p, b = *(const float4*)(p + 4);
  v[0] = a.x; v[1] = a.y; v[2] = a.z; v[3] = a.w;
  v[4] = b.x; v[5] = b.y; v[6] = b.z; v[7] = b.w;
}
__device__ __forceinline__ void stf8(float* __restrict__ p, const float* v) {
  *(float4*)p = make_float4(v[0], v[1], v[2], v[3]);
  *(float4*)(p + 4) = make_float4(v[4], v[5], v[6], v[7]);
}

// ---------------- horizontal pass ------------------------------------------
// block = 256 = 4 rows x 64 lanes; each lane computes 8 consecutive x.
// grid.x = nplanes * 128. LV0 reads f32 inputs (D0 = in1-in0 staged on the
// fly); otherwise reads bf16 cascade plane S. Output tmp is bf16.
template <int R, bool LV0>
__global__ __launch_bounds__(256) void hpass_tele(
    const ushort* __restrict__ S, const float* __restrict__ in0,
    const float* __restrict__ in1, const float* __restrict__ inm,
    ushort* __restrict__ tmp, int cn3, W45 wt) {
  const int bid = swz(blockIdx.x, gridDim.x);
  const int tid = threadIdx.x;
  const int ry = tid >> 6, lr = tid & 63;
  const int p = bid >> 7;
  const int y = ((bid & 127) << 2) + ry;

  __shared__ float lds[4][8 * 70];
  if (LV0) {
    if (p < cn3) {
      const float* rA = in0 + (size_t)p * PLANE + (size_t)y * PW;
      const float* rB = in1 + (size_t)p * PLANE + (size_t)y * PW;
      for (int i = lr; i < PW + 2 * R; i += 64) {
        const int gx = clampi(i - R, PW - 1);
        lds[ry][PHYS(i)] = rB[gx] - rA[gx]; // D0 = img1 - img0
      }
    } else {
      const float* rM = inm + (size_t)(p - cn3) * PLANE + (size_t)y * PW;
      for (int i = lr; i < PW + 2 * R; i += 64) {
        lds[ry][PHYS(i)] = rM[clampi(i - R, PW - 1)];
      }
    }
  } else {
    const ushort* row = S + (size_t)p * PLANE + (size_t)y * PW;
    for (int i = lr; i < PW + 2 * R; i += 64) {
      lds[ry][PHYS(i)] = bf2f(row[clampi(i - R, PW - 1)]);
    }
  }
  __syncthreads();

  const int x0 = lr << 3;
  float win[8 + 2 * R];
#pragma unroll
  for (int j = 0; j < 8 + 2 * R; ++j) win[j] = lds[ry][PHYS(x0 + j)];
  float a[8];
#pragma unroll
  for (int i = 0; i < 8; ++i) a[i] = 0.f;
#pragma unroll
  for (int t = 0; t <= 2 * R; ++t) {
    const float wv = wt.w[t];
#pragma unroll
    for (int i = 0; i < 8; ++i) a[i] = fmaf(wv, win[t + i], a[i]);
  }
  stb8(tmp + (size_t)p * PLANE + (size_t)y * PW + x0, a);
}

// ---------------- vertical pass + telescoped epilogue ----------------------
// block = 512 thr, 64x64 output tile, one plane. tmp/cascade are bf16;
// out accumulator stays f32. Transpose-stash -> float4/uint4 epilogue.
template <int R, int MODE>
__global__ __launch_bounds__(512) void vpass_tele(
    const ushort* __restrict__ tmp, const ushort* __restrict__ S,
    const ushort* __restrict__ Sm, const ushort* __restrict__ Gm4,
    const float* __restrict__ in0, const float* __restrict__ in1,
    const float* __restrict__ inm, ushort* __restrict__ oS,
    ushort* __restrict__ oM, float* __restrict__ outp, int cn3, W45 wt) {
  constexpr int VWIN = 64 + 2 * R;
  __shared__ float buf[VWIN * RS];
  const int bid = swz(blockIdx.x, gridDim.x);
  const int tid = threadIdx.x;
  const int lane = tid & 63, yg = tid >> 6;
  const int p = bid >> 6, t = bid & 63;
  const int x0 = (t & 7) << 6, y0 = (t >> 3) << 6;
  const int ey = tid >> 3, exq = (tid & 7) << 3;
  const size_t erow = (size_t)(y0 + ey) * PW + x0 + exq;

  const bool ismask = (MODE == V_MONLY) || (MODE != V_L3D && p >= cn3);
  const int pm = ismask ? ((MODE == V_MONLY) ? p : p - cn3) : 0;

  // ---- load vertical window (bf16 -> f32 LDS, 16B granules) ----
  {
    const ushort* src = tmp + (size_t)(ismask ? (cn3 + pm) : p) * PLANE;
    for (int idx = tid; idx < VWIN * 8; idx += 512) {
      const int row = idx >> 3, c8 = (idx & 7) << 3;
      const int gy = clampi(y0 + row - R, PH - 1);
      BU b;
      b.q = *(const uint4*)&src[(size_t)gy * PW + x0 + c8];
      float* d = &buf[row * RS + c8];
#pragma unroll
      for (int j = 0; j < 8; ++j) d[j] = bf2f(b.u[j]);
    }
  }
  __syncthreads();

  // ---- V conv: 8 consecutive rows at column `lane` ----
  float win[8 + 2 * R];
#pragma unroll
  for (int j = 0; j < 8 + 2 * R; ++j)
    win[j] = buf[((yg << 3) + j) * RS + lane];
  float b[8];
#pragma unroll
  for (int i = 0; i < 8; ++i) b[i] = 0.f;
#pragma unroll
  for (int t_ = 0; t_ <= 2 * R; ++t_) {
    const float wv = wt.w[t_];
#pragma unroll
    for (int i = 0; i < 8; ++i) b[i] = fmaf(wv, win[t_ + i], b[i]);
  }

  // ---- transpose stash -> each thread owns 8 consecutive x at one y ----
  __syncthreads();
#pragma unroll
  for (int i = 0; i < 8; ++i) buf[lane * 65 + (yg << 3) + i] = b[i];
  __syncthreads();
  float bs[8];
#pragma unroll
  for (int j = 0; j < 8; ++j) bs[j] = buf[(exq + j) * 65 + ey];

  if (MODE == V_MONLY || ismask) {
    stb8(oM + (size_t)pm * PLANE + erow, bs);
    return;
  }

  const int n = p / 3;
  float o[8];
  if (MODE == V_F0) {
    float v0[8], v1[8], m[8];
    ldf8(in0 + (size_t)p * PLANE + erow, v0);
    ldf8(in1 + (size_t)p * PLANE + erow, v1);
    ldf8(inm + (size_t)n * PLANE + erow, m);
#pragma unroll
    for (int j = 0; j < 8; ++j)
      o[j] = v0[j] + m[j] * ((v1[j] - v0[j]) - bs[j]);
    stf8(outp + (size_t)p * PLANE + erow, o);
    stb8(oS + (size_t)p * PLANE + erow, bs);
  } else if (MODE == V_MID) {
    float D[8], m[8], pv[8];
    ldb8(S + (size_t)p * PLANE + erow, D);
    ldb8(Sm + (size_t)n * PLANE + erow, m);
    float* op = outp + (size_t)p * PLANE + erow;
    ldf8(op, pv);
#pragma unroll
    for (int j = 0; j < 8; ++j) o[j] = pv[j] + m[j] * (D[j] - bs[j]);
    stf8(op, o);
    stb8(oS + (size_t)p * PLANE + erow, bs);
  } else { // V_L3D: out += Gm3*(D3 - D4) + Gm4*D4
    float D[8], m3[8], m4[8], pv[8];
    ldb8(S + (size_t)p * PLANE + erow, D);
    ldb8(Sm + (size_t)n * PLANE + erow, m3);
    ldb8(Gm4 + (size_t)n * PLANE + erow, m4);
    float* op = outp + (size_t)p * PLANE + erow;
    ldf8(op, pv);
#pragma unroll
    for (int j = 0; j < 8; ++j)
      o[j] = pv[j] + m3[j] * (D[j] - bs[j]) + m4[j] * bs[j];
    stf8(op, o);
  }
}

// ---------------- host -----------------------------------------------------
static void make_weights(W45& wt, int lvl, int R) {
  double sigma = 1.0;
  for (int i = 0; i < lvl; ++i) sigma *= 2.0;
  double g[45];
  for (int i = 0; i < 45; ++i) {
    double x = i - 22.0;
    g[i] = exp(-(x * x) / (2.0 * sigma * sigma));
  }
  double s = 0.0;
  for (int t = 0; t <= 2 * R; ++t) s += g[t + 22 - R];
  for (int t = 0; t <= 2 * R; ++t) wt.w[t] = (float)(g[t + 22 - R] / s);
}

extern "C" void kernel_launch(void* const* d_in, const int* in_sizes, int n_in,
                              void* d_out, int out_size, void* d_ws,
                              size_t ws_size, hipStream_t stream) {
  const float* img0 = (const float*)d_in[0];
  const float* img1 = (const float*)d_in[1];
  const float* mask = (const float*)d_in[2];
  float* out = (float*)d_out;

  constexpr int R0 = 6, R1 = 10, R2 = 18, R3v = 22;
  W45 w0, w1, w2, w3;
  make_weights(w0, 0, R0);
  make_weights(w1, 1, R1);
  make_weights(w2, 2, R2);
  make_weights(w3, 3, R3v);

  const int NTOT = 16;
  // ws planes/img (bf16): S_A(4) + S_B(4) + tmp(4) = 12 half-planes
  const size_t perImg = (size_t)12 * PLANE * sizeof(ushort);
  int CN = 16;
  while (CN > 1 && (size_t)CN * perImg > ws_size) CN >>= 1;

  for (int s = 0; s < NTOT; s += CN) {
    ushort* SA = (ushort*)d_ws; // [D:3CN][m:CN]
    ushort* SB = SA + (size_t)4 * CN * PLANE;
    ushort* tmp = SB + (size_t)4 * CN * PLANE;

    const float* in0 = img0 + (size_t)s * 3 * PLANE;
    const float* in1 = img1 + (size_t)s * 3 * PLANE;
    const float* inm = mask + (size_t)s * PLANE;
    float* o = out + (size_t)s * 3 * PLANE;

    const int cn3 = 3 * CN;
    ushort* SAm = SA + (size_t)cn3 * PLANE;
    ushort* SBm = SB + (size_t)cn3 * PLANE;
    const ushort* nb = nullptr;
    const float* nf = nullptr;
    const dim3 hb(256), vb(512);
    const int hg = 4 * CN * 128;
    const int vg = 4 * CN * 64;
    const int vgM = CN * 64;
    const int vgD = 3 * CN * 64;

    // L0: stage D0=in1-in0 & mask -> tmp; V: out=i0+m*(D0-D1), SA.D=D1, SA.m=Gm1
    hipLaunchKernelGGL((hpass_tele<R0, true>), dim3(hg), hb, 0, stream, nb, in0,
                       in1, inm, tmp, cn3, w0);
    hipLaunchKernelGGL((vpass_tele<R0, V_F0>), dim3(vg), vb, 0, stream, tmp, nb,
                       nb, nb, in0, in1, inm, SA, SAm, o, cn3, w0);
    // L1: SA -> tmp; out += Gm1*(D1-D2); SB.D=D2, SB.m=Gm2
    hipLaunchKernelGGL((hpass_tele<R1, false>), dim3(hg), hb, 0, stream, SA, nf,
                       nf, nf, tmp, cn3, w1);
    hipLaunchKernelGGL((vpass_tele<R1, V_MID>), dim3(vg), vb, 0, stream, tmp,
                       SA, SAm, nb, nf, nf, nf, SB, SBm, o, cn3, w1);
    // L2: SB -> tmp; out += Gm2*(D2-D3); SA.D=D3, SA.m=Gm3
    hipLaunchKernelGGL((hpass_tele<R2, false>), dim3(hg), hb, 0, stream, SB, nf,
                       nf, nf, tmp, cn3, w2);
    hipLaunchKernelGGL((vpass_tele<R2, V_MID>), dim3(vg), vb, 0, stream, tmp,
                       SB, SBm, nb, nf, nf, nf, SA, SAm, o, cn3, w2);
    // L3: SA -> tmp; Gm4 = V(tmp.m) -> SBm; out += Gm3*(D3-D4)+Gm4*D4
    hipLaunchKernelGGL((hpass_tele<R3v, false>), dim3(hg), hb, 0, stream, SA,
                       nf, nf, nf, tmp, cn3, w3);
    hipLaunchKernelGGL((vpass_tele<R3v, V_MONLY>), dim3(vgM), vb, 0, stream,
                       tmp, nb, nb, nb, nf, nf, nf, (ushort*)nullptr, SBm, o,
                       cn3, w3);
    hipLaunchKernelGGL((vpass_tele<R3v, V_L3D>), dim3(vgD), vb, 0, stream, tmp,
                       SA, SAm, SBm, nf, nf, nf, (ushort*)nullptr,
                       (ushort*)nullptr, o, cn3, w3);
  }
}

// Round 8
// 240.698 us; speedup vs baseline: 12.1925x; 1.1030x over previous
//
#include <hip/hip_runtime.h>

#define PH 512
#define PW 512
#define PLANE (PH * PW)
#define RS 68 /* V-window row stride (floats): conflict-free column reads */
#define PHYS(i) (((i) & 7) * 70 + ((i) >> 3)) /* hpass staged-row swizzle */

enum { V_F0 = 0, V_MID = 1, V_L3D = 2, V_MONLY = 3 };

// ---- compile-time Gaussian weights (literal constants in the ISA) ---------
constexpr double cexp_pos(double z) { // exp(z), z >= 0, Taylor series
  double term = 1.0, sum = 1.0;
  for (int k = 1; k < 160; ++k) {
    term *= z / (double)k;
    sum += term;
  }
  return sum;
}
template <int LVL, int R>
struct WTab {
  float w[2 * R + 1];
  constexpr WTab() : w{} {
    double sig = 1.0;
    for (int i = 0; i < LVL; ++i) sig *= 2.0;
    double g[2 * R + 1] = {};
    double s = 0.0;
    for (int t = 0; t <= 2 * R; ++t) {
      double x = (double)(t - R);
      g[t] = 1.0 / cexp_pos((x * x) / (2.0 * sig * sig));
      s += g[t];
    }
    for (int t = 0; t <= 2 * R; ++t) w[t] = (float)(g[t] / s);
  }
};

__device__ __forceinline__ int clampi(int v, int hi) {
  return v < 0 ? 0 : (v > hi ? hi : v);
}
// XCD-aware bijective chunked swizzle (all grids here are multiples of 8)
__device__ __forceinline__ int swz(int bid, int nwg) {
  const int q = nwg >> 3;
  return (bid & 7) * q + (bid >> 3);
}
__device__ __forceinline__ float bf2f(ushort s) {
  return __uint_as_float((unsigned)s << 16);
}
__device__ __forceinline__ ushort f2bf(float f) { // RNE
  unsigned x = __float_as_uint(f);
  return (ushort)((x + 0x7FFF + ((x >> 16) & 1)) >> 16);
}
union BU { uint4 q; ushort u[8]; };
__device__ __forceinline__ void ldb8(const ushort* __restrict__ p, float* v) {
  BU b;
  b.q = *(const uint4*)p;
#pragma unroll
  for (int j = 0; j < 8; ++j) v[j] = bf2f(b.u[j]);
}
__device__ __forceinline__ void stb8(ushort* __restrict__ p, const float* v) {
  BU b;
#pragma unroll
  for (int j = 0; j < 8; ++j) b.u[j] = f2bf(v[j]);
  *(uint4*)p = b.q;
}
__device__ __forceinline__ void ldf8(const float* __restrict__ p, float* v) {
  float4 a = *(const float4*)p, b = *(const float4*)(p + 4);
  v[0] = a.x; v[1] = a.y; v[2] = a.z; v[3] = a.w;
  v[4] = b.x; v[5] = b.y; v[6] = b.z; v[7] = b.w;
}
__device__ __forceinline__ void stf8(float* __restrict__ p, const float* v) {
  *(float4*)p = make_float4(v[0], v[1], v[2], v[3]);
  *(float4*)(p + 4) = make_float4(v[4], v[5], v[6], v[7]);
}

// ---------------- horizontal pass ------------------------------------------
// block = 256 = 4 rows x 64 lanes; each lane produces 8 consecutive x.
// Staging vectorized 8-wide; replicate-pad halo is edge-value copies.
// Conv is stream-form: one LDS read per window element, literal weights.
template <int LVL, int R, bool LV0>
__global__ __launch_bounds__(256) void hpass_tele(
    const ushort* __restrict__ S, const float* __restrict__ in0,
    const float* __restrict__ in1, const float* __restrict__ inm,
    ushort* __restrict__ tmp, int cn3) {
  constexpr WTab<LVL, R> W;
  const int bid = swz(blockIdx.x, gridDim.x);
  const int tid = threadIdx.x;
  const int ry = tid >> 6, lr = tid & 63;
  const int p = bid >> 7;
  const int y = ((bid & 127) << 2) + ry;
  const int xb = lr << 3;

  __shared__ float lds[4][8 * 70];
  float* L = lds[ry];

  if (LV0) {
    if (p < cn3) {
      const float* rA = in0 + (size_t)p * PLANE + (size_t)y * PW;
      const float* rB = in1 + (size_t)p * PLANE + (size_t)y * PW;
      float a8[8], b8[8];
      ldf8(rA + xb, a8);
      ldf8(rB + xb, b8);
#pragma unroll
      for (int k = 0; k < 8; ++k) L[PHYS(R + xb + k)] = b8[k] - a8[k];
      if (lr < R) L[PHYS(lr)] = rB[0] - rA[0];
      else if (lr >= 32 && lr < 32 + R)
        L[PHYS(R + PW + (lr - 32))] = rB[PW - 1] - rA[PW - 1];
    } else {
      const float* rM = inm + (size_t)(p - cn3) * PLANE + (size_t)y * PW;
      float a8[8];
      ldf8(rM + xb, a8);
#pragma unroll
      for (int k = 0; k < 8; ++k) L[PHYS(R + xb + k)] = a8[k];
      if (lr < R) L[PHYS(lr)] = rM[0];
      else if (lr >= 32 && lr < 32 + R)
        L[PHYS(R + PW + (lr - 32))] = rM[PW - 1];
    }
  } else {
    const ushort* row = S + (size_t)p * PLANE + (size_t)y * PW;
    float a8[8];
    ldb8(row + xb, a8);
#pragma unroll
    for (int k = 0; k < 8; ++k) L[PHYS(R + xb + k)] = a8[k];
    if (lr < R) L[PHYS(lr)] = bf2f(row[0]);
    else if (lr >= 32 && lr < 32 + R)
      L[PHYS(R + PW + (lr - 32))] = bf2f(row[PW - 1]);
  }
  __syncthreads();

  float a[8];
#pragma unroll
  for (int i = 0; i < 8; ++i) a[i] = 0.f;
#pragma unroll
  for (int j = 0; j < 2 * R + 8; ++j) {
    const float v = L[PHYS(xb + j)];
#pragma unroll
    for (int i = 0; i < 8; ++i)
      if (i <= j && j - i <= 2 * R) a[i] = fmaf(W.w[j - i], v, a[i]);
  }
  stb8(tmp + (size_t)p * PLANE + (size_t)y * PW + xb, a);
}

// ---------------- vertical pass + telescoped epilogue ----------------------
// block = 512 thr, 64x64 output tile, one plane. tmp/cascade bf16; out f32.
template <int LVL, int R, int MODE>
__global__ __launch_bounds__(512) void vpass_tele(
    const ushort* __restrict__ tmp, const ushort* __restrict__ Sc,
    const ushort* __restrict__ Sm, const ushort* __restrict__ Gm4,
    const float* __restrict__ in0, const float* __restrict__ in1,
    const float* __restrict__ inm, ushort* __restrict__ oS,
    ushort* __restrict__ oM, float* __restrict__ outp, int cn3) {
  constexpr WTab<LVL, R> W;
  constexpr int VWIN = 64 + 2 * R;
  __shared__ float buf[VWIN * RS];
  const int bid = swz(blockIdx.x, gridDim.x);
  const int tid = threadIdx.x;
  const int lane = tid & 63, yg = tid >> 6;
  const int p = bid >> 6, t = bid & 63;
  const int x0 = (t & 7) << 6, y0 = (t >> 3) << 6;
  const int ey = tid >> 3, exq = (tid & 7) << 3;
  const size_t erow = (size_t)(y0 + ey) * PW + x0 + exq;

  const bool ismask = (MODE == V_MONLY) || (MODE != V_L3D && p >= cn3);
  const int pm = ismask ? ((MODE == V_MONLY) ? p : p - cn3) : 0;

  // ---- load vertical window (bf16 -> f32 LDS, 16B granules) ----
  {
    const ushort* src = tmp + (size_t)(ismask ? (cn3 + pm) : p) * PLANE;
    for (int idx = tid; idx < VWIN * 8; idx += 512) {
      const int row = idx >> 3, c8 = (idx & 7) << 3;
      const int gy = clampi(y0 + row - R, PH - 1);
      BU b;
      b.q = *(const uint4*)&src[(size_t)gy * PW + x0 + c8];
      float* d = &buf[row * RS + c8];
#pragma unroll
      for (int j = 0; j < 8; ++j) d[j] = bf2f(b.u[j]);
    }
  }
  __syncthreads();

  // ---- V conv: stream-form, 8 consecutive rows at column `lane` ----
  float b[8];
#pragma unroll
  for (int i = 0; i < 8; ++i) b[i] = 0.f;
#pragma unroll
  for (int j = 0; j < 2 * R + 8; ++j) {
    const float v = buf[((yg << 3) + j) * RS + lane];
#pragma unroll
    for (int i = 0; i < 8; ++i)
      if (i <= j && j - i <= 2 * R) b[i] = fmaf(W.w[j - i], v, b[i]);
  }

  // ---- transpose stash -> each thread owns 8 consecutive x at one y ----
  __syncthreads();
#pragma unroll
  for (int i = 0; i < 8; ++i) buf[lane * 65 + (yg << 3) + i] = b[i];
  __syncthreads();
  float bs[8];
#pragma unroll
  for (int j = 0; j < 8; ++j) bs[j] = buf[(exq + j) * 65 + ey];

  if (MODE == V_MONLY || ismask) {
    stb8(oM + (size_t)pm * PLANE + erow, bs);
    return;
  }

  const int n = p / 3;
  float o[8];
  if (MODE == V_F0) {
    float v0[8], v1[8], m[8];
    ldf8(in0 + (size_t)p * PLANE + erow, v0);
    ldf8(in1 + (size_t)p * PLANE + erow, v1);
    ldf8(inm + (size_t)n * PLANE + erow, m);
#pragma unroll
    for (int j = 0; j < 8; ++j)
      o[j] = v0[j] + m[j] * ((v1[j] - v0[j]) - bs[j]);
    stf8(outp + (size_t)p * PLANE + erow, o);
    stb8(oS + (size_t)p * PLANE + erow, bs);
  } else if (MODE == V_MID) {
    float D[8], m[8], pv[8];
    ldb8(Sc + (size_t)p * PLANE + erow, D);
    ldb8(Sm + (size_t)n * PLANE + erow, m);
    float* op = outp + (size_t)p * PLANE + erow;
    ldf8(op, pv);
#pragma unroll
    for (int j = 0; j < 8; ++j) o[j] = pv[j] + m[j] * (D[j] - bs[j]);
    stf8(op, o);
    stb8(oS + (size_t)p * PLANE + erow, bs);
  } else { // V_L3D: out += Gm3*(D3 - D4) + Gm4*D4
    float D[8], m3[8], m4[8], pv[8];
    ldb8(Sc + (size_t)p * PLANE + erow, D);
    ldb8(Sm + (size_t)n * PLANE + erow, m3);
    ldb8(Gm4 + (size_t)n * PLANE + erow, m4);
    float* op = outp + (size_t)p * PLANE + erow;
    ldf8(op, pv);
#pragma unroll
    for (int j = 0; j < 8; ++j)
      o[j] = pv[j] + m3[j] * (D[j] - bs[j]) + m4[j] * bs[j];
    stf8(op, o);
  }
}

// ---------------- host -----------------------------------------------------
extern "C" void kernel_launch(void* const* d_in, const int* in_sizes, int n_in,
                              void* d_out, int out_size, void* d_ws,
                              size_t ws_size, hipStream_t stream) {
  const float* img0 = (const float*)d_in[0];
  const float* img1 = (const float*)d_in[1];
  const float* mask = (const float*)d_in[2];
  float* out = (float*)d_out;

  constexpr int R0 = 6, R1 = 10, R2 = 18, R3v = 22;

  const int NTOT = 16;
  // ws planes/img (bf16): S_A(4) + S_B(4) + tmp(4) = 12 half-planes
  const size_t perImg = (size_t)12 * PLANE * sizeof(ushort);
  int CN = 16;
  while (CN > 1 && (size_t)CN * perImg > ws_size) CN >>= 1;

  for (int s = 0; s < NTOT; s += CN) {
    ushort* SA = (ushort*)d_ws; // [D:3CN][m:CN]
    ushort* SB = SA + (size_t)4 * CN * PLANE;
    ushort* tmp = SB + (size_t)4 * CN * PLANE;

    const float* in0 = img0 + (size_t)s * 3 * PLANE;
    const float* in1 = img1 + (size_t)s * 3 * PLANE;
    const float* inm = mask + (size_t)s * PLANE;
    float* o = out + (size_t)s * 3 * PLANE;

    const int cn3 = 3 * CN;
    ushort* SAm = SA + (size_t)cn3 * PLANE;
    ushort* SBm = SB + (size_t)cn3 * PLANE;
    const ushort* nb = nullptr;
    const float* nf = nullptr;
    const dim3 hb(256), vb(512);
    const int hg = 4 * CN * 128;
    const int vg = 4 * CN * 64;
    const int vgM = CN * 64;
    const int vgD = 3 * CN * 64;

    // L0: stage D0=in1-in0 & mask -> tmp; V: out=i0+m*(D0-D1), SA.D=D1, SA.m=Gm1
    hipLaunchKernelGGL((hpass_tele<0, R0, true>), dim3(hg), hb, 0, stream, nb,
                       in0, in1, inm, tmp, cn3);
    hipLaunchKernelGGL((vpass_tele<0, R0, V_F0>), dim3(vg), vb, 0, stream, tmp,
                       nb, nb, nb, in0, in1, inm, SA, SAm, o, cn3);
    // L1: SA -> tmp; out += Gm1*(D1-D2); SB.D=D2, SB.m=Gm2
    hipLaunchKernelGGL((hpass_tele<1, R1, false>), dim3(hg), hb, 0, stream, SA,
                       nf, nf, nf, tmp, cn3);
    hipLaunchKernelGGL((vpass_tele<1, R1, V_MID>), dim3(vg), vb, 0, stream, tmp,
                       SA, SAm, nb, nf, nf, nf, SB, SBm, o, cn3);
    // L2: SB -> tmp; out += Gm2*(D2-D3); SA.D=D3, SA.m=Gm3
    hipLaunchKernelGGL((hpass_tele<2, R2, false>), dim3(hg), hb, 0, stream, SB,
                       nf, nf, nf, tmp, cn3);
    hipLaunchKernelGGL((vpass_tele<2, R2, V_MID>), dim3(vg), vb, 0, stream, tmp,
                       SB, SBm, nb, nf, nf, nf, SA, SAm, o, cn3);
    // L3: SA -> tmp; Gm4 = V(tmp.m) -> SBm; out += Gm3*(D3-D4)+Gm4*D4
    hipLaunchKernelGGL((hpass_tele<3, R3v, false>), dim3(hg), hb, 0, stream, SA,
                       nf, nf, nf, tmp, cn3);
    hipLaunchKernelGGL((vpass_tele<3, R3v, V_MONLY>), dim3(vgM), vb, 0, stream,
                       tmp, nb, nb, nb, nf, nf, nf, (ushort*)nullptr, SBm, o,
                       cn3);
    hipLaunchKernelGGL((vpass_tele<3, R3v, V_L3D>), dim3(vgD), vb, 0, stream,
                       tmp, SA, SAm, SBm, nf, nf, nf, (ushort*)nullptr,
                       (ushort*)nullptr, o, cn3);
  }
}